// Round 11
// baseline (109.909 us; speedup 1.0000x reference)
//
#include <hip/hip_runtime.h>
#include <math.h>

#define BB 4
#define LL 1024
#define EE 512
#define HH 8
#define DD 64
#define MAXREL 512

typedef unsigned short u16;
typedef __attribute__((ext_vector_type(8))) short bf16x8;
typedef __attribute__((ext_vector_type(4))) float f32x4;

__device__ __forceinline__ u16 f2bf(float f) {
    unsigned int u = __float_as_uint(f);
    unsigned int r = (u + 0x7FFFu + ((u >> 16) & 1u)) >> 16;
    return (u16)r;
}
__device__ __forceinline__ float bf2f(u16 b) {
    return __uint_as_float(((unsigned int)b) << 16);
}
__device__ __forceinline__ bf16x8 ldf8_bf(const float* p) {
    const float4 a = *(const float4*)(p);
    const float4 b = *(const float4*)(p + 4);
    bf16x8 r;
    r[0] = (short)f2bf(a.x); r[1] = (short)f2bf(a.y);
    r[2] = (short)f2bf(a.z); r[3] = (short)f2bf(a.w);
    r[4] = (short)f2bf(b.x); r[5] = (short)f2bf(b.y);
    r[6] = (short)f2bf(b.z); r[7] = (short)f2bf(b.w);
    return r;
}

#define MF(A, B, C) __builtin_amdgcn_mfma_f32_16x16x32_bf16((A), (B), (C), 0, 0, 0)
// exp(x/8) = exp2(x * log2(e)/8)
#define EXPSC 0.1803368801111244f

// ---------------- projection via MFMA ----------------
__global__ __launch_bounds__(256) void proj_mfma_kernel(
    const float* __restrict__ q_in, const float* __restrict__ k_in, const float* __restrict__ v_in,
    const float* __restrict__ Wq, const float* __restrict__ bq,
    const float* __restrict__ Wk, const float* __restrict__ bk,
    const float* __restrict__ Wv, const float* __restrict__ bv,
    u16* __restrict__ qb, u16* __restrict__ kb, u16* __restrict__ vtb)
{
    int bh = blockIdx.x; int b = bh >> 3; int h = bh & 7;
    int l0 = blockIdx.y * 64;
    int t = threadIdx.x; int w = t >> 6; int lane = t & 63;
    int lg = lane >> 4, lc = lane & 15;
    int lt = l0 + w * 16;

    bf16x8 wq[4][2], wk[4][2], wv[4][2];
    #pragma unroll
    for (int dt = 0; dt < 4; ++dt)
        #pragma unroll
        for (int kc = 0; kc < 2; ++kc) {
            int d = dt * 16 + lc, ko = kc * 32 + lg * 8;
            wq[dt][kc] = ldf8_bf(Wq + d * DD + ko);
            wk[dt][kc] = ldf8_bf(Wk + d * DD + ko);
            wv[dt][kc] = ldf8_bf(Wv + d * DD + ko);
        }
    size_t xrow = ((size_t)b * LL + lt + lc) * EE + h * DD;
    bf16x8 xq[2], xk[2], xv[2];
    #pragma unroll
    for (int kc = 0; kc < 2; ++kc) {
        int ko = kc * 32 + lg * 8;
        xq[kc] = ldf8_bf(q_in + xrow + ko);
        xk[kc] = ldf8_bf(k_in + xrow + ko);
        xv[kc] = ldf8_bf(v_in + xrow + ko);
    }

    f32x4 aq[4] = {}, ak[4] = {}, av[4] = {};
    #pragma unroll
    for (int dt = 0; dt < 4; ++dt) {
        aq[dt] = MF(wq[dt][0], xq[0], aq[dt]);
        aq[dt] = MF(wq[dt][1], xq[1], aq[dt]);
        ak[dt] = MF(wk[dt][0], xk[0], ak[dt]);
        ak[dt] = MF(wk[dt][1], xk[1], ak[dt]);
        av[dt] = MF(xv[0], wv[dt][0], av[dt]);
        av[dt] = MF(xv[1], wv[dt][1], av[dt]);
    }

    #pragma unroll
    for (int dt = 0; dt < 4; ++dt) {
        u16 tq[4], tk[4], tv[4];
        #pragma unroll
        for (int r = 0; r < 4; ++r) {
            int d = dt * 16 + lg * 4 + r;
            tq[r] = f2bf(aq[dt][r] + bq[d]);
            tk[r] = f2bf(ak[dt][r] + bk[d]);
            tv[r] = f2bf(av[dt][r] + bv[dt * 16 + lc]);
        }
        size_t o = ((size_t)bh * LL + lt + lc) * DD + dt * 16 + lg * 4;
        *(uint2*)&qb[o] = *(uint2*)tq;
        *(uint2*)&kb[o] = *(uint2*)tk;
        size_t ov = ((size_t)bh * DD + dt * 16 + lc) * LL + lt + lg * 4;
        *(uint2*)&vtb[ov] = *(uint2*)tv;
    }
}

// ---------------- prep: padded bf16 rel tables + bf16 Wfc ----------------
__global__ __launch_bounds__(256) void prep_kernel(
    const float* __restrict__ relk, const float* __restrict__ relv, const float* __restrict__ Wfc,
    u16* __restrict__ relk_pad, u16* __restrict__ relvt_pad, u16* __restrict__ wfcb)
{
    int idx = blockIdx.x * 256 + threadIdx.x;   // 1024 blocks -> 262144
    if (idx < 2048 * DD) {
        int r = idx >> 6, d = idx & 63;
        int j = r - 512; j = j < 0 ? 0 : (j > 2 * MAXREL ? 2 * MAXREL : j);
        relk_pad[idx] = f2bf(relk[j * DD + d]);
        int dd = idx >> 11, c = idx & 2047;
        int j2 = c - 512; j2 = j2 < 0 ? 0 : (j2 > 2 * MAXREL ? 2 * MAXREL : j2);
        relvt_pad[idx] = f2bf(relv[j2 * DD + dd]);
    }
    if (idx < EE * EE) wfcb[idx] = f2bf(Wfc[idx]);
}

// ---------------- fused attention: 64-row q-tile, 8 waves, softmax-behind pipeline ----------------
// grid (B*H, L/64), block 512 (8 waves). Wave (qh,cw,rw): q-rows qh*32+rw*16 (+16),
// k-cols cw*32 (+32), PV partial over all 64 d; cw-pairs combined in epilogue.
// Iter c: scores+softmax of chunk c+1 (Ks double-buffered), PV of chunk c.
__global__ __launch_bounds__(512) void attn_mfma_kernel(
    const u16* __restrict__ qb, const u16* __restrict__ kb, const u16* __restrict__ vtb,
    const int* __restrict__ mask,
    const u16* __restrict__ relk_pad, const u16* __restrict__ relvt_pad,
    u16* __restrict__ attn_out)
{
    __shared__ __align__(16) char smem[76288];
    // Ks0: 0..9216, Ks1: 9216..18432 [64][72] each
    u16* Vts  = (u16*)(smem + 18432);     // [64][72]   9216
    u16* RVts = (u16*)(smem + 27648);     // [64][152] 19456 (cols 0..127 staged, 128..151 zero)
    float* lred = (float*)(smem + 75776); // [128]
    float* obuf = (float*)smem;           // epilogue reuse [64][68] f32 (over Ks)

    int bh = blockIdx.x, b = bh >> 3, h = bh & 7;
    int q0 = blockIdx.y * 64;
    int t = threadIdx.x, lane = t & 63, w = t >> 6;
    int qh = w >> 2, cw = (w >> 1) & 1, rw = w & 1;
    int rbase = qh * 32 + rw * 16, c0a = cw * 32;
    int lg = lane >> 4, lc = lane & 15;
    int ub_k = c0a - rbase + 16;          // rel-K gather window base (may be negative)
    int ub_v = c0a - rbase + 48;          // rel-V LDS window base, in {0,16,...,80}
    size_t bhL = (size_t)bh * LL;
    const u16* kb_bh = kb + bhL * DD;
    const u16* vt_bh = vtb + (size_t)bh * DD * LL;
    const int* mk_b = mask + b * LL;
    u16* Pw  = (u16*)(smem + 47104) + w * 640;   // [16][40] per wave (8 waves, 10240 B)
    u16* Pqw = (u16*)(smem + 57344) + w * 1152;  // [16][72] per wave (18432 B)

    // staging indices (512 threads)
    int sr = t >> 3, ss = (t & 7) * 8;           // K/V: 64 rows x 8 slots
    int rv_row = t >> 3, rv_q = (t & 7) * 16;    // RV: 64 rows x 8 thread-pairs x 16 cols
    const u16* rvg = relvt_pad + (size_t)rv_row * 2048 + rv_q;
    u16* rvl = RVts + rv_row * 152 + rv_q;

    const u16* qrow = qb + (bhL + q0 + rbase + lc) * DD;
    bf16x8 qf0 = *(const bf16x8*)&qrow[lg * 8];
    bf16x8 qf1 = *(const bf16x8*)&qrow[32 + lg * 8];

    f32x4 s0, s1, g0, g1, g2;
    bf16x8 rk0, rk1, rk2, rk3, rk4, rk5;
    f32x4 oacc[4] = {};
    float lacc[4] = {0.f, 0.f, 0.f, 0.f};
    int delta0 = lc - lg * 4;

#define LOAD_RK(SB) do { \
    const u16* rkp_ = relk_pad + (size_t)((SB) + ub_k + lc) * DD + lg * 8; \
    rk0 = *(const bf16x8*)&rkp_[0]; \
    rk1 = *(const bf16x8*)&rkp_[32]; \
    rk2 = *(const bf16x8*)&rkp_[16 * DD]; \
    rk3 = *(const bf16x8*)&rkp_[16 * DD + 32]; \
    rk4 = *(const bf16x8*)&rkp_[32 * DD]; \
    rk5 = *(const bf16x8*)&rkp_[32 * DD + 32]; \
} while (0)

#define DO_SCORES(KBASE) do { \
    const u16* kp0_ = (KBASE) + (c0a + lc) * 72; \
    const u16* kp1_ = (KBASE) + (c0a + 16 + lc) * 72; \
    s0 = (f32x4){0.f,0.f,0.f,0.f}; s1 = s0; g0 = s0; g1 = s0; g2 = s0; \
    __builtin_amdgcn_s_setprio(1); \
    s0 = MF(qf0, *(const bf16x8*)&kp0_[lg * 8], s0); \
    s0 = MF(qf1, *(const bf16x8*)&kp0_[32 + lg * 8], s0); \
    s1 = MF(qf0, *(const bf16x8*)&kp1_[lg * 8], s1); \
    s1 = MF(qf1, *(const bf16x8*)&kp1_[32 + lg * 8], s1); \
    g0 = MF(qf0, rk0, g0); g0 = MF(qf1, rk1, g0); \
    g1 = MF(qf0, rk2, g1); g1 = MF(qf1, rk3, g1); \
    g2 = MF(qf0, rk4, g2); g2 = MF(qf1, rk5, g2); \
    __builtin_amdgcn_s_setprio(0); \
} while (0)

#define DO_SOFTMAX(MB0, MB1) do { \
    _Pragma("unroll") \
    for (int r = 0; r < 4; ++r) { \
        int d_ = delta0 - r; \
        int src_ = (lane & 48) | (d_ & 15); \
        float a0_ = __shfl(g0[r], src_, 64); \
        float a1_ = __shfl(g1[r], src_, 64); \
        float a2_ = __shfl(g2[r], src_, 64); \
        float gv0_ = (d_ >= 0) ? a1_ : a0_; \
        float gv1_ = (d_ >= 0) ? a2_ : a1_; \
        float p0_ = exp2f((s0[r] + (MB0) + gv0_) * EXPSC); \
        float p1_ = exp2f((s1[r] + (MB1) + gv1_) * EXPSC); \
        u16 pb0_ = f2bf(p0_), pb1_ = f2bf(p1_); \
        lacc[r] += p0_ + p1_; \
        int row_ = lg * 4 + r; \
        Pw[row_ * 40 + lc] = pb0_; \
        Pw[row_ * 40 + 16 + lc] = pb1_; \
        Pqw[row_ * 72 + lc - row_ + 16] = pb0_; \
        Pqw[row_ * 72 + 32 + lc - row_] = pb1_; \
    } \
} while (0)

    // ---- prolog ----
    #pragma unroll
    for (int i = 0; i < 3; ++i) {        // zero this wave's Pqw (144 uint4)
        int u = lane + i * 64;
        if (u < 144) *(uint4*)&Pqw[u * 8] = make_uint4(0, 0, 0, 0);
    }
    if (t < 192) {                        // zero RVts cols 128..151
        int row = t / 3, j = t - row * 3;
        *(uint4*)&RVts[row * 152 + 128 + j * 8] = make_uint4(0, 0, 0, 0);
    }
    int sb0 = 992 - q0;                   // rel-K pad base for chunk 0
    int sv0 = 960 - q0;                   // rel-V pad base for chunk 0
    {
        u16* Ks0 = (u16*)smem;
        u16* Ks1 = (u16*)(smem + 9216);
        *(uint4*)&Ks0[sr * 72 + ss] = *(const uint4*)&kb_bh[(size_t)sr * DD + ss];
        *(uint4*)&Ks1[sr * 72 + ss] = *(const uint4*)&kb_bh[(size_t)(64 + sr) * DD + ss];
        *(uint4*)&Vts[sr * 72 + ss] = *(const uint4*)&vt_bh[(size_t)sr * LL + ss];
        *(uint4*)&rvl[0] = *(const uint4*)&rvg[sv0];
        *(uint4*)&rvl[8] = *(const uint4*)&rvg[sv0 + 8];
    }
    LOAD_RK(sb0);
    float mbp0 = (mk_b[c0a + lc] != 0) ? 0.f : -1e20f;
    float mbp1 = (mk_b[c0a + 16 + lc] != 0) ? 0.f : -1e20f;
    __syncthreads();
    DO_SCORES((const u16*)smem);          // chunk 0
    LOAD_RK(sb0 + 64);                    // rel-K(1)
    DO_SOFTMAX(mbp0, mbp1);               // P(0)

    // ---- main loop: iter c does scores/softmax(c+1) + PV(c) ----
    #pragma unroll 1
    for (int c = 0; c < 16; ++c) {
        int k0 = c * 64;
        int sb_ = k0 - q0 + 992;
        uint4 rK0, rV0, rRV0, rRV1;
        float mbn0 = 0.f, mbn1 = 0.f;
        if (c < 14)
            rK0 = *(const uint4*)&kb_bh[(size_t)(k0 + 128 + sr) * DD + ss];
        if (c < 15) {
            int k0n = k0 + 64;
            int svn = k0n - q0 + 960;
            rV0  = *(const uint4*)&vt_bh[(size_t)sr * LL + k0n + ss];
            rRV0 = *(const uint4*)&rvg[svn];
            rRV1 = *(const uint4*)&rvg[svn + 8];
            mbn0 = (mk_b[k0n + c0a + lc] != 0) ? 0.f : -1e20f;
            mbn1 = (mk_b[k0n + c0a + 16 + lc] != 0) ? 0.f : -1e20f;
        }

        // P(c) fragments (written last iteration / prolog; wave-local)
        bf16x8 pa  = *(const bf16x8*)&Pw[lc * 40 + lg * 8];
        bf16x8 pq0 = *(const bf16x8*)&Pqw[lc * 72 + lg * 8];
        bf16x8 pq1 = *(const bf16x8*)&Pqw[lc * 72 + 32 + lg * 8];

        if (c < 15) {
            const u16* kcur = (const u16*)(smem + ((c + 1) & 1) * 9216);
            DO_SCORES(kcur);                   // chunk c+1
            if (c < 14) LOAD_RK(sb_ + 128);    // rel-K(c+2)
        }

        // PV(c) — independent of scores(c+1)
        __builtin_amdgcn_s_setprio(1);
        #pragma unroll
        for (int dt = 0; dt < 4; ++dt) {
            const u16* vp = &Vts[(dt * 16 + lc) * 72 + c0a];
            const u16* rp = &RVts[(dt * 16 + lc) * 152 + ub_v];
            oacc[dt] = MF(pa,  *(const bf16x8*)&vp[lg * 8], oacc[dt]);
            oacc[dt] = MF(pq0, *(const bf16x8*)&rp[lg * 8], oacc[dt]);
            oacc[dt] = MF(pq1, *(const bf16x8*)&rp[32 + lg * 8], oacc[dt]);
        }
        __builtin_amdgcn_s_setprio(0);

        if (c < 15) {
            DO_SOFTMAX(mbn0, mbn1);            // P(c+1), overlaps PV drain
            __syncthreads();                   // all waves done reading chunk c tiles
            if (c < 14) {
                u16* kwr = (u16*)(smem + (c & 1) * 9216);
                *(uint4*)&kwr[sr * 72 + ss] = rK0;
            }
            *(uint4*)&Vts[sr * 72 + ss] = rV0;
            *(uint4*)&rvl[0] = rRV0;
            *(uint4*)&rvl[8] = rRV1;
            __syncthreads();                   // chunk c+1 tiles visible
        }
    }
#undef LOAD_RK
#undef DO_SCORES
#undef DO_SOFTMAX

    // ---- epilogue: row-sum + cw-pair combine ----
    #pragma unroll
    for (int m2 = 1; m2 <= 8; m2 <<= 1) {
        #pragma unroll
        for (int r = 0; r < 4; ++r) lacc[r] += __shfl_xor(lacc[r], m2);
    }
    __syncthreads();
    if (lc == 0) {
        #pragma unroll
        for (int r = 0; r < 4; ++r) lred[cw * 64 + rbase + lg * 4 + r] = lacc[r];
    }
    __syncthreads();
    if (cw == 1) {
        #pragma unroll
        for (int dt = 0; dt < 4; ++dt)
            #pragma unroll
            for (int r = 0; r < 4; ++r)
                obuf[(rbase + lg * 4 + r) * 68 + dt * 16 + lc] = oacc[dt][r];
    }
    __syncthreads();
    if (cw == 0) {
        float inv[4];
        #pragma unroll
        for (int r = 0; r < 4; ++r) {
            int row = rbase + lg * 4 + r;
            inv[r] = 1.0f / (lred[row] + lred[64 + row]);
        }
        #pragma unroll
        for (int dt = 0; dt < 4; ++dt) {
            #pragma unroll
            for (int r = 0; r < 4; ++r) {
                int row = rbase + lg * 4 + r;
                float v = (oacc[dt][r] + obuf[row * 68 + dt * 16 + lc]) * inv[r];
                attn_out[((size_t)b * LL + q0 + row) * EE + h * DD + dt * 16 + lc] = f2bf(v);
            }
        }
    }
}

// ---------------- final FC via MFMA: out = X @ Wfc.T + bfc ----------------
__global__ __launch_bounds__(256) void fc_mfma_kernel(
    const u16* __restrict__ Xb, const u16* __restrict__ Wb,
    const float* __restrict__ bfc, float* __restrict__ out)
{
    __shared__ u16 As[128][72];
    __shared__ u16 Bs[128][72];
    int m0 = blockIdx.x * 128, n0 = blockIdx.y * 128;
    int t = threadIdx.x, lane = t & 63, w = t >> 6;
    int rw = w & 1, cw = w >> 1;
    int lg = lane >> 4, lc = lane & 15;
    f32x4 acc[4][4] = {};

    for (int kt = 0; kt < EE; kt += 64) {
        __syncthreads();
        #pragma unroll
        for (int i = 0; i < 4; ++i) {
            int unit = i * 256 + t;
            int row = unit >> 3, s = unit & 7;
            *(uint4*)&As[row][s * 8] = *(const uint4*)&Xb[(size_t)(m0 + row) * EE + kt + s * 8];
            *(uint4*)&Bs[row][s * 8] = *(const uint4*)&Wb[(size_t)(n0 + row) * EE + kt + s * 8];
        }
        __syncthreads();
        #pragma unroll
        for (int kc = 0; kc < 2; ++kc) {
            bf16x8 af[4], bf[4];
            #pragma unroll
            for (int i = 0; i < 4; ++i) {
                af[i] = *(const bf16x8*)&As[rw * 64 + i * 16 + lc][kc * 32 + lg * 8];
                bf[i] = *(const bf16x8*)&Bs[cw * 64 + i * 16 + lc][kc * 32 + lg * 8];
            }
            #pragma unroll
            for (int mi = 0; mi < 4; ++mi)
                #pragma unroll
                for (int ni = 0; ni < 4; ++ni)
                    acc[mi][ni] = MF(af[mi], bf[ni], acc[mi][ni]);
        }
    }
    #pragma unroll
    for (int mi = 0; mi < 4; ++mi) {
        #pragma unroll
        for (int ni = 0; ni < 4; ++ni) {
            int n = n0 + cw * 64 + ni * 16 + lc;
            float bias = bfc[n];
            #pragma unroll
            for (int r = 0; r < 4; ++r) {
                int m = m0 + rw * 64 + mi * 16 + lg * 4 + r;
                out[(size_t)m * EE + n] = acc[mi][ni][r] + bias;
            }
        }
    }
}

extern "C" void kernel_launch(void* const* d_in, const int* in_sizes, int n_in,
                              void* d_out, int out_size, void* d_ws, size_t ws_size,
                              hipStream_t stream) {
    const float* query = (const float*)d_in[0];
    const float* key   = (const float*)d_in[1];
    const float* value = (const float*)d_in[2];
    const int*   mask  = (const int*)d_in[3];
    const float* Wq  = (const float*)d_in[4];
    const float* bq  = (const float*)d_in[5];
    const float* Wk  = (const float*)d_in[6];
    const float* bk  = (const float*)d_in[7];
    const float* Wv  = (const float*)d_in[8];
    const float* bv  = (const float*)d_in[9];
    const float* Wfc = (const float*)d_in[10];
    const float* bfc = (const float*)d_in[11];
    const float* relk = (const float*)d_in[12];
    const float* relv = (const float*)d_in[13];
    float* out = (float*)d_out;

    char* ws = (char*)d_ws;
    u16* qb        = (u16*)(ws);                            // 4 MB
    u16* kb        = (u16*)(ws + (4u << 20));               // 4 MB
    u16* vtb       = (u16*)(ws + (8u << 20));               // 4 MB
    u16* attnb     = (u16*)(ws + (12u << 20));              // 4 MB
    u16* relk_pad  = (u16*)(ws + (16u << 20));              // 256 KB
    u16* relvt_pad = (u16*)(ws + (16u << 20) + 262144);     // 256 KB
    u16* wfcb      = (u16*)(ws + (16u << 20) + 524288);     // 512 KB

    proj_mfma_kernel<<<dim3(BB * HH, LL / 64), 256, 0, stream>>>(
        query, key, value, Wq, bq, Wk, bk, Wv, bv, qb, kb, vtb);
    prep_kernel<<<1024, 256, 0, stream>>>(relk, relv, Wfc, relk_pad, relvt_pad, wfcb);
    attn_mfma_kernel<<<dim3(BB * HH, LL / 64), 512, 0, stream>>>(
        qb, kb, vtb, mask, relk_pad, relvt_pad, attnb);
    fc_mfma_kernel<<<dim3(BB * LL / 128, EE / 128), 256, 0, stream>>>(attnb, wfcb, bfc, out);
}